// Round 1
// baseline (88.133 us; speedup 1.0000x reference)
//
#include <hip/hip_runtime.h>

// MPSLayer: out[b,o] = sum_{l,r} state[b,l,r] * proj[r,l,o] + bias[o]
// where state = ones(32,32) @ prod_i (x[b,i] * C_i).
//
// Key identities (see journal):
//   rows of state are identical  ->  state[b,l,r] = v_b[r]
//   v_b = s_b * u,  s_b = prod_i x[b,i],  u^T = 1^T prod_i C_i
//   out[b,o] = s_b * q[o] + bias[o],  q[o] = sum_r u[r] * P2[r,o],
//   P2[r,o] = sum_l proj[r,l,o]
//
// ws layout (floats):
//   [0,      16384) : M_seg[16][32][32]  (segment products of cores)
//   [16384,  32768) : P2[32][512]
//   [32768,  33792) : s[1024]
//   [33792,  34304) : q[512]
// total 137,216 bytes

#define NSEG   16
#define SEGLEN 16

__global__ __launch_bounds__(256) void mps_k1(const float* __restrict__ x,
                                              const float* __restrict__ cores,
                                              const float* __restrict__ proj,
                                              float* __restrict__ ws) {
    const int blk = blockIdx.x;
    const int t   = threadIdx.x;

    if (blk < NSEG) {
        // ---- role A: segment product M = C[16s] @ C[16s+1] @ ... @ C[16s+15]
        __shared__ float Ms[32][33];
        __shared__ float Cs[32][33];
        const float* cbase = cores + (size_t)blk * SEGLEN * 1024;
        const int l  = t >> 3;        // 0..31
        const int r0 = (t & 7) * 4;   // 0,4,...,28

        {
            float4 v = *(const float4*)(cbase + l * 32 + r0);
            Ms[l][r0 + 0] = v.x; Ms[l][r0 + 1] = v.y;
            Ms[l][r0 + 2] = v.z; Ms[l][r0 + 3] = v.w;
        }
        __syncthreads();

        for (int i = 1; i < SEGLEN; ++i) {
            float4 c = *(const float4*)(cbase + i * 1024 + l * 32 + r0);
            Cs[l][r0 + 0] = c.x; Cs[l][r0 + 1] = c.y;
            Cs[l][r0 + 2] = c.z; Cs[l][r0 + 3] = c.w;
            __syncthreads();

            float a0 = 0.f, a1 = 0.f, a2 = 0.f, a3 = 0.f;
            #pragma unroll
            for (int k = 0; k < 32; ++k) {
                float m = Ms[l][k];
                a0 = fmaf(m, Cs[k][r0 + 0], a0);
                a1 = fmaf(m, Cs[k][r0 + 1], a1);
                a2 = fmaf(m, Cs[k][r0 + 2], a2);
                a3 = fmaf(m, Cs[k][r0 + 3], a3);
            }
            __syncthreads();
            Ms[l][r0 + 0] = a0; Ms[l][r0 + 1] = a1;
            Ms[l][r0 + 2] = a2; Ms[l][r0 + 3] = a3;
            __syncthreads();
        }

        float4 o4;
        o4.x = Ms[l][r0 + 0]; o4.y = Ms[l][r0 + 1];
        o4.z = Ms[l][r0 + 2]; o4.w = Ms[l][r0 + 3];
        *(float4*)(ws + blk * 1024 + l * 32 + r0) = o4;

    } else if (blk < NSEG + 32) {
        // ---- role B: P2[r,o] = sum_l proj[r,l,o]   (16384 outputs / 8192 thr)
        const int base = (blk - NSEG) * 512;
        #pragma unroll
        for (int it = 0; it < 2; ++it) {
            int e = base + it * 256 + t;      // 0..16383
            int r = e >> 9;
            int o = e & 511;
            float sum = 0.f;
            #pragma unroll
            for (int l = 0; l < 32; ++l)
                sum += proj[(size_t)(r * 32 + l) * 512 + o];
            ws[16384 + e] = sum;
        }

    } else {
        // ---- role C: s[b] = prod_i x[b,i]; one 64-lane wave per batch row
        const int wave = t >> 6;          // 0..3
        const int lane = t & 63;
        const int b    = (blk - (NSEG + 32)) * 4 + wave;  // 0..1023
        float4 v = *(const float4*)(x + (size_t)b * 256 + lane * 4);
        float p = v.x * v.y * v.z * v.w;
        #pragma unroll
        for (int off = 32; off >= 1; off >>= 1)
            p *= __shfl_xor(p, off, 64);
        if (lane == 0) ws[32768 + b] = p;
    }
}

__global__ __launch_bounds__(512) void mps_k2(float* __restrict__ ws) {
    __shared__ float u[32];
    __shared__ float un[32];
    const int t = threadIdx.x;

    // u0[r] = column sums of M_0   (== 1^T M_0)
    if (t < 32) {
        float sum = 0.f;
        #pragma unroll
        for (int k = 0; k < 32; ++k) sum += ws[k * 32 + t];
        u[t] = sum;
    }
    __syncthreads();

    for (int sgi = 1; sgi < NSEG; ++sgi) {
        if (t < 32) {
            const float* M = ws + sgi * 1024;
            float sum = 0.f;
            #pragma unroll
            for (int k = 0; k < 32; ++k) sum = fmaf(u[k], M[k * 32 + t], sum);
            un[t] = sum;
        }
        __syncthreads();
        if (t < 32) u[t] = un[t];
        __syncthreads();
    }

    // q[o] = sum_r u[r] * P2[r,o]
    const float* P2 = ws + 16384;
    float sum = 0.f;
    #pragma unroll
    for (int r = 0; r < 32; ++r) sum = fmaf(u[r], P2[r * 512 + t], sum);
    ws[33792 + t] = sum;
}

__global__ __launch_bounds__(256) void mps_k3(const float* __restrict__ ws,
                                              const float* __restrict__ bias,
                                              float* __restrict__ out) {
    const int idx = (blockIdx.x * 256 + threadIdx.x) * 4;  // [0, 524288)
    const int b = idx >> 9;
    const int o = idx & 511;
    const float s  = ws[32768 + b];
    const float4 q4 = *(const float4*)(ws + 33792 + o);
    const float4 bi = *(const float4*)(bias + o);
    float4 r;
    r.x = fmaf(s, q4.x, bi.x);
    r.y = fmaf(s, q4.y, bi.y);
    r.z = fmaf(s, q4.z, bi.z);
    r.w = fmaf(s, q4.w, bi.w);
    *(float4*)(out + idx) = r;
}

extern "C" void kernel_launch(void* const* d_in, const int* in_sizes, int n_in,
                              void* d_out, int out_size, void* d_ws, size_t ws_size,
                              hipStream_t stream) {
    const float* x     = (const float*)d_in[0];   // [1024, 256]
    const float* cores = (const float*)d_in[1];   // [256, 32, 32]
    const float* proj  = (const float*)d_in[2];   // [32, 32, 512]
    const float* bias  = (const float*)d_in[3];   // [512]
    float* out = (float*)d_out;                    // [1024, 512]
    float* ws  = (float*)d_ws;

    hipLaunchKernelGGL(mps_k1, dim3(NSEG + 32 + 256), dim3(256), 0, stream,
                       x, cores, proj, ws);
    hipLaunchKernelGGL(mps_k2, dim3(1), dim3(512), 0, stream, ws);
    hipLaunchKernelGGL(mps_k3, dim3(512), dim3(256), 0, stream, ws, bias, out);
}

// Round 2
// 82.243 us; speedup vs baseline: 1.0716x; 1.0716x over previous
//
#include <hip/hip_runtime.h>

// MPSLayer: out[b,o] = s_b * q[o] + bias[o]
//   s_b = prod_i x[b,i]
//   u^T = 1^T prod_i C_i   (computed as 16 segment products, then folded)
//   q[o] = sum_r u[r] * P2[r,o],  P2[r,o] = sum_l proj[r,l,o]
//
// ws layout (floats):
//   [0,     16384) : M_seg[16][32][32]
//   [16384, 32768) : P2[32][512]
//   [32768, 33792) : s[1024]

#define NSEG   16
#define SEGLEN 16

__global__ __launch_bounds__(512) void mps_k1(const float* __restrict__ x,
                                              const float* __restrict__ cores,
                                              const float* __restrict__ proj,
                                              float* __restrict__ ws) {
    const int blk = blockIdx.x;
    const int t   = threadIdx.x;

    if (blk < NSEG) {
        // ---- role A: segment product M = C[16s] @ ... @ C[16s+15]
        // Prefetch all 16 cores (64 KB) to LDS, then chain with ping-pong state.
        __shared__ float Craw[SEGLEN * 1024];
        __shared__ float M0[32][33];
        __shared__ float M1[32][33];
        const float* cbase = cores + (size_t)blk * (SEGLEN * 1024);
        #pragma unroll
        for (int j = 0; j < 8; ++j) {
            int f = j * 2048 + t * 4;
            *(float4*)&Craw[f] = *(const float4*)(cbase + f);
        }
        const int l  = t >> 4;        // 0..31
        const int c0 = (t & 15) * 2;  // 0,2,...,30
        __syncthreads();

        M0[l][c0]     = Craw[l * 32 + c0];
        M0[l][c0 + 1] = Craw[l * 32 + c0 + 1];
        __syncthreads();

        float (*pin)[33]  = M0;
        float (*pout)[33] = M1;
        for (int i = 1; i < SEGLEN; ++i) {
            const float* Ci = &Craw[i * 1024];
            float a0 = 0.f, a1 = 0.f, b0 = 0.f, b1 = 0.f;
            #pragma unroll
            for (int k = 0; k < 32; k += 2) {
                float p0 = pin[l][k];
                float p1 = pin[l][k + 1];
                float2 c00 = *(const float2*)&Ci[k * 32 + c0];
                float2 c10 = *(const float2*)&Ci[(k + 1) * 32 + c0];
                a0 = fmaf(p0, c00.x, a0);
                a1 = fmaf(p0, c00.y, a1);
                b0 = fmaf(p1, c10.x, b0);
                b1 = fmaf(p1, c10.y, b1);
            }
            pout[l][c0]     = a0 + b0;
            pout[l][c0 + 1] = a1 + b1;
            __syncthreads();   // covers RAW on pout and WAR on pin
            float (*tmp)[33] = pin; pin = pout; pout = tmp;
        }
        *(float2*)(ws + blk * 1024 + l * 32 + c0) =
            make_float2(pin[l][c0], pin[l][c0 + 1]);

    } else if (blk < NSEG + 32) {
        // ---- role B: P2[r,o] = sum_l proj[r,l,o]  (16384 outputs, 1/thread)
        const int e = (blk - NSEG) * 512 + t;
        const int r = e >> 9;
        const int o = e & 511;
        float s0 = 0.f, s1 = 0.f, s2 = 0.f, s3 = 0.f;
        #pragma unroll
        for (int l = 0; l < 32; l += 4) {
            s0 += proj[(size_t)(r * 32 + l) * 512 + o];
            s1 += proj[(size_t)(r * 32 + l + 1) * 512 + o];
            s2 += proj[(size_t)(r * 32 + l + 2) * 512 + o];
            s3 += proj[(size_t)(r * 32 + l + 3) * 512 + o];
        }
        ws[16384 + e] = (s0 + s1) + (s2 + s3);

    } else {
        // ---- role C: s[b] = prod_i x[b,i]; one 64-lane wave per batch row
        const int wave = t >> 6;          // 0..7
        const int lane = t & 63;
        const int b    = (blk - (NSEG + 32)) * 8 + wave;  // 0..1023
        float4 v = *(const float4*)(x + (size_t)b * 256 + lane * 4);
        float p = v.x * v.y * v.z * v.w;
        #pragma unroll
        for (int off = 32; off >= 1; off >>= 1)
            p *= __shfl_xor(p, off, 64);
        if (lane == 0) ws[32768 + b] = p;
    }
}

__global__ __launch_bounds__(512) void mps_k2(const float* __restrict__ ws,
                                              const float* __restrict__ bias,
                                              float* __restrict__ out) {
    __shared__ float M[NSEG * 1024];
    __shared__ float u[32];
    const int t = threadIdx.x;

    // prefetch all 16 segment matrices (16 KB) to LDS
    #pragma unroll
    for (int j = 0; j < 8; ++j) {
        int f = j * 2048 + t * 4;
        *(float4*)&M[f] = *(const float4*)(ws + f);
    }
    __syncthreads();

    // wave 0, lanes 0..31: fold u^T = 1^T M_0 ... M_15, all from LDS.
    // Single-wave lockstep -> no barriers needed inside the chain.
    if (t < 32) {
        float s0 = 0.f, s1 = 0.f, s2 = 0.f, s3 = 0.f;
        #pragma unroll
        for (int k = 0; k < 32; k += 4) {
            s0 += M[(k + 0) * 32 + t];
            s1 += M[(k + 1) * 32 + t];
            s2 += M[(k + 2) * 32 + t];
            s3 += M[(k + 3) * 32 + t];
        }
        u[t] = (s0 + s1) + (s2 + s3);
        for (int i = 1; i < NSEG; ++i) {
            const float* Mi = &M[i * 1024];
            float a0 = 0.f, a1 = 0.f, a2 = 0.f, a3 = 0.f;
            #pragma unroll
            for (int k = 0; k < 32; k += 4) {
                a0 = fmaf(u[k + 0], Mi[(k + 0) * 32 + t], a0);
                a1 = fmaf(u[k + 1], Mi[(k + 1) * 32 + t], a1);
                a2 = fmaf(u[k + 2], Mi[(k + 2) * 32 + t], a2);
                a3 = fmaf(u[k + 3], Mi[(k + 3) * 32 + t], a3);
            }
            // all lanes' reads of u[] precede this store in lockstep order
            u[t] = (a0 + a1) + (a2 + a3);
        }
    }
    __syncthreads();

    // q[t] = sum_r u[r] * P2[r,t]; then 8 output rows per block
    const float* P2 = ws + 16384;
    float q0 = 0.f, q1 = 0.f, q2 = 0.f, q3 = 0.f;
    #pragma unroll
    for (int r = 0; r < 32; r += 4) {
        q0 = fmaf(u[r + 0], P2[(r + 0) * 512 + t], q0);
        q1 = fmaf(u[r + 1], P2[(r + 1) * 512 + t], q1);
        q2 = fmaf(u[r + 2], P2[(r + 2) * 512 + t], q2);
        q3 = fmaf(u[r + 3], P2[(r + 3) * 512 + t], q3);
    }
    const float qv = (q0 + q1) + (q2 + q3);
    const float bv = bias[t];

    const int b0 = blockIdx.x * 8;
    #pragma unroll
    for (int j = 0; j < 8; ++j) {
        const float s = ws[32768 + b0 + j];
        out[(size_t)(b0 + j) * 512 + t] = fmaf(s, qv, bv);
    }
}

extern "C" void kernel_launch(void* const* d_in, const int* in_sizes, int n_in,
                              void* d_out, int out_size, void* d_ws, size_t ws_size,
                              hipStream_t stream) {
    const float* x     = (const float*)d_in[0];   // [1024, 256]
    const float* cores = (const float*)d_in[1];   // [256, 32, 32]
    const float* proj  = (const float*)d_in[2];   // [32, 32, 512]
    const float* bias  = (const float*)d_in[3];   // [512]
    float* out = (float*)d_out;                    // [1024, 512]
    float* ws  = (float*)d_ws;

    hipLaunchKernelGGL(mps_k1, dim3(NSEG + 32 + 128), dim3(512), 0, stream,
                       x, cores, proj, ws);
    hipLaunchKernelGGL(mps_k2, dim3(128), dim3(512), 0, stream, ws, bias, out);
}